// Round 8
// baseline (248.009 us; speedup 1.0000x reference)
//
#include <hip/hip_runtime.h>

typedef __bf16 bf16;
typedef __bf16 bf16x4 __attribute__((ext_vector_type(4)));
typedef __bf16 bf16x8 __attribute__((ext_vector_type(8)));
typedef _Float16 f16;
typedef _Float16 f16x2 __attribute__((ext_vector_type(2)));
typedef _Float16 f16x4 __attribute__((ext_vector_type(4)));
typedef _Float16 f16x8 __attribute__((ext_vector_type(8)));
typedef float f32x4 __attribute__((ext_vector_type(4)));
typedef unsigned int u32x4 __attribute__((ext_vector_type(4)));

#define MFMA16 __builtin_amdgcn_mfma_f32_16x16x32_bf16
#define MFMA16H __builtin_amdgcn_mfma_f32_16x16x32_f16

// async 16B/lane global->LDS copy; HW scatters lane i to lds + i*16 (wave-uniform base)
__device__ __forceinline__ void async16(void* lds, const void* g) {
    __builtin_amdgcn_global_load_lds((const __attribute__((address_space(1))) unsigned int*)g,
                                     (__attribute__((address_space(3))) unsigned int*)lds, 16, 0, 0);
}

// packed f32x2 -> f16x2 (cvt_pkrtz returns __fp16-based vector; bit-cast to _Float16-based)
__device__ __forceinline__ f16x2 pkrtz(float a, float b) {
    return __builtin_bit_cast(f16x2, __builtin_amdgcn_cvt_pkrtz(a, b));
}

__device__ __forceinline__ float fdot2h(f16x2 a, f16x2 b, float c) {
#if __has_builtin(__builtin_amdgcn_fdot2)
    return __builtin_amdgcn_fdot2(a, b, c, false);
#else
    return c + (float)a[0] * (float)b[0] + (float)a[1] * (float)b[1];
#endif
}

// ---------------------------------------------------------------------------
// K0 "prep": weight cvt (blocks 0..255) + three activation transposes
// (s3: 256..767, s4: 768..1023, s5: 1024..1151).
__global__ __launch_bounds__(256) void k_prep(const float* __restrict__ qw, const float* __restrict__ kw,
                                              const float* __restrict__ vw, const float* __restrict__ ow,
                                              bf16* __restrict__ Wb,
                                              const float* __restrict__ s3, const float* __restrict__ s4,
                                              const float* __restrict__ s5,
                                              bf16* __restrict__ s3t, bf16* __restrict__ s45t) {
    __shared__ float T[64][65];
    int bx = blockIdx.x, t = threadIdx.x;
    if (bx < 256) {
        int tt = bx * 256 + t;
        const float* srcs[4] = {qw, kw, vw, ow};
        int which = tt >> 14;
        int idx = (tt & 16383) * 4;
        f32x4 v = *(const f32x4*)(srcs[which] + idx);
        bf16x4 o;
        o[0] = (bf16)v[0]; o[1] = (bf16)v[1]; o[2] = (bf16)v[2]; o[3] = (bf16)v[3];
        *(bf16x4*)(Wb + (size_t)which * 65536 + idx) = o;
        return;
    }
    const float* src; bf16* dst; int N, dstRows, rowOff, x, y, z;
    if (bx < 768)       { int i = bx - 256;  src = s3; dst = s3t;  N = 4096; dstRows = 4096; rowOff = 0;    x = i & 63; y = (i >> 6) & 3; z = i >> 8; }
    else if (bx < 1024) { int i = bx - 768;  src = s4; dst = s45t; N = 2048; dstRows = 3072; rowOff = 0;    x = i & 31; y = (i >> 5) & 3; z = i >> 7; }
    else                { int i = bx - 1024; src = s5; dst = s45t; N = 1024; dstRows = 3072; rowOff = 2048; x = i & 15; y = (i >> 4) & 3; z = i >> 6; }
    int c0 = y * 64, n0 = x * 64, b = z;
    const float* s = src + ((size_t)b * 256 + c0) * N + n0;
#pragma unroll
    for (int i = 0; i < 4; i++) {
        int flat = i * 256 + t;
        int row = flat >> 4;
        int col = (flat & 15) * 4;
        f32x4 v = *(const f32x4*)(s + (size_t)row * N + col);
        T[row][col + 0] = v[0]; T[row][col + 1] = v[1];
        T[row][col + 2] = v[2]; T[row][col + 3] = v[3];
    }
    __syncthreads();
#pragma unroll
    for (int i = 0; i < 4; i++) {
        int flat = i * 256 + t;
        int nrow = flat >> 4;
        int c4 = (flat & 15) * 4;
        bf16x4 o;
        o[0] = (bf16)T[c4 + 0][nrow]; o[1] = (bf16)T[c4 + 1][nrow];
        o[2] = (bf16)T[c4 + 2][nrow]; o[3] = (bf16)T[c4 + 3][nrow];
        *(bf16x4*)(dst + ((size_t)(b * dstRows + rowOff + n0 + nrow)) * 256 + c0 + c4) = o;
    }
}

// ---------------------------------------------------------------------------
// K1 "qkv": Q blocks 0..511 (mode 0), K 512..895 (mode 1), V 896..1279 (mode 2).
// mode 0: Q bf16 [bh][n][32], pre-scaled by 32^-.5*log2e.
// mode 1: K bf16 [bh][n'][32], n' row-permuted within 32-blocks (u=n&31 ->
//         np = ((u>>2)&1)<<4 | (u>>3)<<2 | (u&3)) so two 16-row S^T tiles
//         concatenate into a K=32 MFMA B-operand.
// mode 2: V f16 [bh][32 d][3072 kn], kn permuted per 64-chunk by a d-keyed
//         XOR on 8-elem granules: col = (n&~63) + ((g^(d&7))<<3) + (n&7).
__global__ __launch_bounds__(256) void k_qkv(const bf16* __restrict__ Wb,
                                             const bf16* __restrict__ s3t, const bf16* __restrict__ s45t,
                                             const float* __restrict__ qb, const float* __restrict__ kb,
                                             const float* __restrict__ vb,
                                             bf16* __restrict__ Qb, bf16* __restrict__ Kb,
                                             f16* __restrict__ Vtb, float qscale) {
    int i = blockIdx.x;
    int mode, n0, m0, b, Nrows;
    const bf16 *A, *Bt; const float* bias; float oscale = 1.0f;
    if (i < 512) {
        mode = 0; A = Wb; Bt = s3t; bias = qb; Nrows = 4096; oscale = qscale;
        n0 = (i & 63) * 64; m0 = ((i >> 6) & 3) * 64; b = i >> 8;
    } else if (i < 896) {
        unsigned j = i - 512;
        mode = 1; A = Wb + 65536; Bt = s45t; bias = kb; Nrows = 3072;
        n0 = (j % 48u) * 64; unsigned rr = j / 48u; m0 = (rr & 3) * 64; b = rr >> 2;
    } else {
        unsigned j = i - 896;
        mode = 2; A = Wb + 131072; Bt = s45t; bias = vb; Nrows = 3072;
        n0 = (j % 48u) * 64; unsigned rr = j / 48u; m0 = (rr & 3) * 64; b = rr >> 2;
    }
    __shared__ bf16 As[64 * 40];
    __shared__ bf16 Bs[64 * 40];
    int t = threadIdx.x;
    int w = t >> 6, lane = t & 63;
    int lrow = lane & 15, lk = lane >> 4;
    f32x4 acc[4] = {};
    int r = t >> 2, cc = (t & 3) * 8;
    for (int kc = 0; kc < 256; kc += 32) {
        u32x4 va = *(const u32x4*)(A + (size_t)(m0 + r) * 256 + kc + cc);
        u32x4 vbv = *(const u32x4*)(Bt + ((size_t)b * Nrows + n0 + r) * 256 + kc + cc);
        *(u32x4*)(As + r * 40 + cc) = va;
        *(u32x4*)(Bs + r * 40 + cc) = vbv;
        __syncthreads();
        bf16x8 af = *(const bf16x8*)(As + (w * 16 + lrow) * 40 + lk * 8);
#pragma unroll
        for (int ct = 0; ct < 4; ct++) {
            bf16x8 bfr = *(const bf16x8*)(Bs + (ct * 16 + lrow) * 40 + lk * 8);
            acc[ct] = MFMA16(af, bfr, acc[ct], 0, 0, 0);
        }
        __syncthreads();
    }
    // C/D layout: col = lane&15, row = (lane>>4)*4 + reg  [verified m89/m91]
    int o0 = m0 + w * 16 + lk * 4;
    f32x4 b4 = *(const f32x4*)(bias + o0);
    int head = o0 >> 5;
#pragma unroll
    for (int ct = 0; ct < 4; ct++) {
        int n = n0 + ct * 16 + lrow;
        if (mode == 0) {
            int dd = o0 & 31;
            bf16x4 pv;
#pragma unroll
            for (int j = 0; j < 4; j++) pv[j] = (bf16)((acc[ct][j] + b4[j]) * oscale);
            *(bf16x4*)(Qb + ((size_t)(b * 8 + head) * 4096 + n) * 32 + dd) = pv;
        } else if (mode == 1) {
            int dd = o0 & 31;
            int u = n & 31;
            int np = (n & ~31) | (((u >> 2) & 1) << 4) | ((u >> 3) << 2) | (u & 3);
            bf16x4 pv;
#pragma unroll
            for (int j = 0; j < 4; j++) pv[j] = (bf16)(acc[ct][j] + b4[j]);
            *(bf16x4*)(Kb + ((size_t)(b * 8 + head) * 3072 + np) * 32 + dd) = pv;
        } else {
            int g = (n & 63) >> 3;
#pragma unroll
            for (int j = 0; j < 4; j++) {
                int dd = (o0 & 31) + j;
                int col = (n & ~63) + ((g ^ (dd & 7)) << 3) + (n & 7);
                Vtb[((size_t)(b * 8 + head) * 32 + dd) * 3072 + col] = (f16)(acc[ct][j] + b4[j]);
            }
        }
    }
}

// ---------------------------------------------------------------------------
// K2: attention. S^T = K·Q^T (bf16 16x16x32); K's global row-perm makes two
// 16-row S^T tiles' exp2'd C/D registers a bit-exact K=32 f16 B-operand, so
// PV runs full-rate via mfma_f32_16x16x32_f16 with V^T as A: out^T[d][q] +=
// V^T·P^T, P register-resident. L row-sums: fdot2 + 2 shuffles.
// Block = 4 waves x 64q = 256 q; kn chunk 64, dbuf async LDS; split-kn=6.
// LDS union: epilogue transpose buffer Tq aliases Ks/Vs (only used after the
// K-loop's final barrier) -> 16.9 KB total -> 6 blocks/CU at grid 1536.
__global__ __launch_bounds__(256, 6) void k_attn(const bf16* __restrict__ Q, const bf16* __restrict__ K,
                                                 const f16* __restrict__ Vt,
                                                 f16* __restrict__ Opart, float* __restrict__ Lsum) {
    int bh = blockIdx.y;
    int q0 = blockIdx.x * 256;
    int sp = blockIdx.z;
    int kn0 = sp * 512;
    int t = threadIdx.x, w = t >> 6, lane = t & 63;
    int lrow = lane & 15, lk = lane >> 4;
    __shared__ __align__(16) char smem[16896];
    bf16* Ks = (bf16*)smem;          // [2][64*32]
    f16* Vs = (f16*)(smem + 8192);   // [2][32*64]
    f16* Tq = (f16*)smem;            // epilogue: [4][32*66] (aliases Ks/Vs)
    const bf16* kbase = K + (size_t)bh * 3072 * 32;
    const f16* vbase = Vt + (size_t)bh * 32 * 3072;
    const bf16* kg = kbase + (size_t)(kn0 + w * 16 + (lane >> 2)) * 32 + (lane & 3) * 8;
    const f16* vg = vbase + (size_t)(w * 8 + (lane >> 3)) * 3072 + kn0 + (lane & 7) * 8;
    // Q as B-operand: B[k=d=lk*8+j][n=q=lrow], one frag per 16-q group
    bf16x8 aq[4];
#pragma unroll
    for (int qg = 0; qg < 4; ++qg)
        aq[qg] = *(const bf16x8*)(Q + ((size_t)bh * 4096 + q0 + w * 64 + qg * 16 + lrow) * 32 + lk * 8);
    f32x4 accO[4][2] = {};   // [q-group][d-half], out^T: row=d_local, col=q
    float lsum[4] = {0.f, 0.f, 0.f, 0.f};
    f32x4 zero = {};
    f16x2 one2; one2[0] = (f16)1.f; one2[1] = (f16)1.f;
    int vkey = lrow & 7;     // V image XOR key = d&7 (same for both d-halves)
    async16(Ks + w * 512, kg);
    async16(Vs + w * 512, vg);
    __syncthreads();
    for (int c = 0; c < 8; ++c) {
        int buf = c & 1;
        if (c < 7) {
            async16(Ks + (buf ^ 1) * 2048 + w * 512, kg + (size_t)(c + 1) * 64 * 32);
            async16(Vs + (buf ^ 1) * 2048 + w * 512, vg + (c + 1) * 64);
        }
        const bf16* ksb = Ks + buf * 2048;
        const f16* vsb = Vs + buf * 2048;
#pragma unroll
        for (int p = 0; p < 2; ++p) {   // two 32-kn chunks
            f32x4 s[2][4];
#pragma unroll
            for (int t2 = 0; t2 < 2; ++t2) {
                bf16x8 kf = *(const bf16x8*)(ksb + (p * 32 + t2 * 16 + lrow) * 32 + lk * 8);
#pragma unroll
                for (int qg = 0; qg < 4; ++qg) s[t2][qg] = MFMA16(kf, aq[qg], zero, 0, 0, 0);
            }
            f16x8 p8[4];
#pragma unroll
            for (int qg = 0; qg < 4; ++qg) {
                f16x2 h0 = pkrtz(__builtin_amdgcn_exp2f(s[0][qg][0]), __builtin_amdgcn_exp2f(s[0][qg][1]));
                f16x2 h1 = pkrtz(__builtin_amdgcn_exp2f(s[0][qg][2]), __builtin_amdgcn_exp2f(s[0][qg][3]));
                f16x2 h2 = pkrtz(__builtin_amdgcn_exp2f(s[1][qg][0]), __builtin_amdgcn_exp2f(s[1][qg][1]));
                f16x2 h3 = pkrtz(__builtin_amdgcn_exp2f(s[1][qg][2]), __builtin_amdgcn_exp2f(s[1][qg][3]));
                f16x8 pk;
                pk[0] = h0[0]; pk[1] = h0[1]; pk[2] = h1[0]; pk[3] = h1[1];
                pk[4] = h2[0]; pk[5] = h2[1]; pk[6] = h3[0]; pk[7] = h3[1];
                p8[qg] = pk;
                lsum[qg] = fdot2h(h0, one2, lsum[qg]);
                lsum[qg] = fdot2h(h1, one2, lsum[qg]);
                lsum[qg] = fdot2h(h2, one2, lsum[qg]);
                lsum[qg] = fdot2h(h3, one2, lsum[qg]);
            }
#pragma unroll
            for (int dh = 0; dh < 2; ++dh) {
                f16x8 vf = *(const f16x8*)(vsb + (dh * 16 + lrow) * 64 + ((((p << 2) | lk) ^ vkey) << 3));
#pragma unroll
                for (int qg = 0; qg < 4; ++qg)
                    accO[qg][dh] = MFMA16H(vf, p8[qg], accO[qg][dh], 0, 0, 0);
            }
        }
        __syncthreads();   // also guards Tq aliasing: all Ks/Vs reads done before epilogue
    }
    // L: reduce per-lane partials over lk (lanes lrow, lrow+16, +32, +48)
    int sb = sp * 16 + bh;
#pragma unroll
    for (int qg = 0; qg < 4; ++qg) {
        lsum[qg] += __shfl_xor(lsum[qg], 16, 64);
        lsum[qg] += __shfl_xor(lsum[qg], 32, 64);
    }
    if (lane < 16) {
#pragma unroll
        for (int qg = 0; qg < 4; ++qg)
            Lsum[(size_t)sb * 4096 + q0 + w * 64 + qg * 16 + lane] = lsum[qg];
    }
    // O epilogue: same-wave LDS transpose [d][q] -> coalesced [q][d] f16 stores
    f16* tw = Tq + w * 2112;
#pragma unroll
    for (int qg = 0; qg < 4; ++qg)
#pragma unroll
        for (int dh = 0; dh < 2; ++dh)
#pragma unroll
            for (int i = 0; i < 4; ++i)
                tw[(dh * 16 + lk * 4 + i) * 66 + qg * 16 + lrow] = (f16)accO[qg][dh][i];
    int q4 = (lane & 15) * 4, dgrp = (lane >> 4) * 8;
#pragma unroll
    for (int qq = 0; qq < 4; ++qq) {
        f16x8 ov;
#pragma unroll
        for (int dj = 0; dj < 8; ++dj) ov[dj] = tw[(dgrp + dj) * 66 + q4 + qq];
        *(f16x8*)(Opart + ((size_t)sb * 4096 + q0 + w * 64 + q4 + qq) * 32 + dgrp) = ov;
    }
}

// ---------------------------------------------------------------------------
// K3 "oln": o-projection + split-kn combine + bias + residual + LayerNorm +
// output transpose, all in one kernel. Block = 32 q x 256 c (full channel row
// -> LN is block-local). Residual from bf16 s3t [b][n][256] (error << thresh).
// GEMM acc stays in registers; LN via LDS tile; out [b][c][n] written
// coalesced along n. 256 blocks.
__global__ __launch_bounds__(256) void k_oln(const bf16* __restrict__ A, const f16* __restrict__ Opart,
                                             const float* __restrict__ Ls, const float* __restrict__ bias,
                                             const bf16* __restrict__ s3t,
                                             const float* __restrict__ lnw, const float* __restrict__ lnb,
                                             float* __restrict__ out) {
    int i = blockIdx.x;
    int b = i >> 7, n0 = (i & 127) * 32;
    __shared__ __align__(16) char smem[34176];
    bf16* As = (bf16*)smem;                 // 256 x 40 bf16 = 20480 B (GEMM phase)
    bf16* Bs = (bf16*)(smem + 20480);       // 32 x 40 bf16 = 2560 B
    float* T = (float*)smem;                // 32 x 257 f32 = 32896 B (LN phase, aliases As/Bs)
    float* ps = (float*)(smem + 32896);     // [4 w][32 n] partial sums
    float* pq = (float*)(smem + 33408);     // [4 w][32 n] partial sumsq
    float* mu_s = (float*)(smem + 33920);   // [32]
    float* rs_s = (float*)(smem + 34048);   // [32]
    int t = threadIdx.x, w = t >> 6, lane = t & 63;
    int lrow = lane & 15, lk = lane >> 4;
    f32x4 acc[4][2] = {};                   // [mt: c-64-block][ct: 16-q group]
    int rB = t >> 3, cgB = (t & 7) * 4;     // B staging: row q, 4-d group
    int q = n0 + rB;
    const size_t SPS = (size_t)16 * 4096 * 32;   // Opart sp stride (elems)
    for (int kc = 0; kc < 256; kc += 32) {
        int bh = b * 8 + (kc >> 5);
        // A staging: thread t = row o, 32 c = 4 x 16B
        const bf16* ar = A + (size_t)t * 256 + kc;
        u32x4 va0 = *(const u32x4*)(ar);
        u32x4 va1 = *(const u32x4*)(ar + 8);
        u32x4 va2 = *(const u32x4*)(ar + 16);
        u32x4 va3 = *(const u32x4*)(ar + 24);
        // B combine: sum 6 split-kn partials, divide by total L
        float l = 0.f;
#pragma unroll
        for (int sp = 0; sp < 6; ++sp) l += Ls[(size_t)(sp * 16 + bh) * 4096 + q];
        float rl = 1.0f / l;
        const f16* obp = Opart + ((size_t)bh * 4096 + q) * 32 + cgB;
        f32x4 sv = {};
#pragma unroll
        for (int sp = 0; sp < 6; ++sp) {
            f16x4 av = *(const f16x4*)(obp + sp * SPS);
#pragma unroll
            for (int j = 0; j < 4; ++j) sv[j] += (float)av[j];
        }
        bf16x4 bb;
#pragma unroll
        for (int j = 0; j < 4; ++j) bb[j] = (bf16)(sv[j] * rl);
        *(u32x4*)(As + t * 40 + 0) = va0;
        *(u32x4*)(As + t * 40 + 8) = va1;
        *(u32x4*)(As + t * 40 + 16) = va2;
        *(u32x4*)(As + t * 40 + 24) = va3;
        *(bf16x4*)(Bs + rB * 40 + cgB) = bb;
        __syncthreads();
#pragma unroll
        for (int mt = 0; mt < 4; ++mt) {
            bf16x8 af = *(const bf16x8*)(As + (mt * 64 + w * 16 + lrow) * 40 + lk * 8);
#pragma unroll
            for (int ct = 0; ct < 2; ++ct) {
                bf16x8 bfr = *(const bf16x8*)(Bs + (ct * 16 + lrow) * 40 + lk * 8);
                acc[mt][ct] = MFMA16(af, bfr, acc[mt][ct], 0, 0, 0);
            }
        }
        __syncthreads();   // last iter: frees As/Bs for the T alias below
    }
    // epilogue: bias + residual; write raw values to T; accumulate LN stats
    float wsum[2] = {0.f, 0.f}, wsq[2] = {0.f, 0.f};
#pragma unroll
    for (int ct = 0; ct < 2; ++ct) {
        int n = ct * 16 + lrow;
#pragma unroll
        for (int mt = 0; mt < 4; ++mt) {
            int c0 = mt * 64 + w * 16 + lk * 4;
            f32x4 b4 = *(const f32x4*)(bias + c0);
            bf16x4 rv = *(const bf16x4*)(s3t + ((size_t)b * 4096 + n0 + n) * 256 + c0);
#pragma unroll
            for (int j = 0; j < 4; ++j) {
                float v = acc[mt][ct][j] + b4[j] + (float)rv[j];
                T[n * 257 + c0 + j] = v;
                wsum[ct] += v;
                wsq[ct] += v * v;
            }
        }
    }
#pragma unroll
    for (int ct = 0; ct < 2; ++ct) {
        wsum[ct] += __shfl_xor(wsum[ct], 16, 64);
        wsum[ct] += __shfl_xor(wsum[ct], 32, 64);
        wsq[ct] += __shfl_xor(wsq[ct], 16, 64);
        wsq[ct] += __shfl_xor(wsq[ct], 32, 64);
    }
    if (lk == 0) {
#pragma unroll
        for (int ct = 0; ct < 2; ++ct) {
            ps[w * 32 + ct * 16 + lrow] = wsum[ct];
            pq[w * 32 + ct * 16 + lrow] = wsq[ct];
        }
    }
    __syncthreads();
    if (t < 32) {
        float S = ps[t] + ps[32 + t] + ps[64 + t] + ps[96 + t];
        float Q2 = pq[t] + pq[32 + t] + pq[64 + t] + pq[96 + t];
        float m = S * (1.0f / 256.0f);
        mu_s[t] = m;
        rs_s[t] = rsqrtf(Q2 * (1.0f / 256.0f) - m * m + 1e-5f);
    }
    __syncthreads();
    // write out[b][c][n0..n0+31], coalesced along n: thread -> (c = t>>3 + 32*cc8, n4 = (t&7)*4)
    int cb = t >> 3, n4 = (t & 7) * 4;
#pragma unroll
    for (int cc8 = 0; cc8 < 8; ++cc8) {
        int c = cb + cc8 * 32;
        float wv = lnw[c], bv = lnb[c];
        f32x4 o;
#pragma unroll
        for (int k2 = 0; k2 < 4; ++k2)
            o[k2] = (T[(n4 + k2) * 257 + c] - mu_s[n4 + k2]) * rs_s[n4 + k2] * wv + bv;
        *(f32x4*)(out + ((size_t)b * 256 + c) * 4096 + n0 + n4) = o;
    }
}

// ---------------------------------------------------------------------------
extern "C" void kernel_launch(void* const* d_in, const int* in_sizes, int n_in,
                              void* d_out, int out_size, void* d_ws, size_t ws_size,
                              hipStream_t stream) {
    const float* s3  = (const float*)d_in[0];
    const float* s4  = (const float*)d_in[1];
    const float* s5  = (const float*)d_in[2];
    const float* qw  = (const float*)d_in[3];
    const float* qb  = (const float*)d_in[4];
    const float* kw  = (const float*)d_in[5];
    const float* kb  = (const float*)d_in[6];
    const float* vw  = (const float*)d_in[7];
    const float* vb  = (const float*)d_in[8];
    const float* ow  = (const float*)d_in[9];
    const float* ob  = (const float*)d_in[10];
    const float* lnw = (const float*)d_in[11];
    const float* lnb = (const float*)d_in[12];
    float* out = (float*)d_out;
    char* ws = (char*)d_ws;

    // workspace layout (~43 MB peak):
    bf16* Wb    = (bf16*)(ws);                          // 512 KB @ 0
    bf16* s3t   = (bf16*)(ws + (512ull << 10));         // 4 MB  @ 0.5 MB (live till k_oln)
    bf16* s45t  = (bf16*)(ws + (4608ull << 10));        // 3 MB  @ 4.5 MB
    bf16* Qb    = (bf16*)(ws + (7680ull << 10));        // 4 MB  @ 7.5 MB
    bf16* Kb    = Qb + (2ull * 8 * 4096 * 32);          // 3 MB  @ 11.5 MB
    f16*  Vtb   = (f16*)(Kb + (2ull * 8 * 3072 * 32));  // 3 MB  @ 14.5 MB
    f16*  Opart = (f16*)(ws + (17920ull << 10));        // 24 MB @ 17.5 MB (f16 [6sp][16bh][4096q][32d])
    float* Lsum = (float*)(ws + (42496ull << 10));      // 1.5 MB @ 41.5 MB

    const float qscale = 0.17677669529663688f * 1.4426950408889634f;  // 32^-0.5 * log2(e)

    k_prep<<<1152, 256, 0, stream>>>(qw, kw, vw, ow, Wb, s3, s4, s5, s3t, s45t);
    k_qkv<<<1280, 256, 0, stream>>>(Wb, s3t, s45t, qb, kb, vb, Qb, Kb, Vtb, qscale);
    k_attn<<<dim3(16, 16, 6), 256, 0, stream>>>(Qb, Kb, Vtb, Opart, Lsum);
    k_oln<<<256, 256, 0, stream>>>(Wb + 196608, Opart, Lsum, ob, s3t, lnw, lnb, out);
}

// Round 9
// 144.534 us; speedup vs baseline: 1.7159x; 1.7159x over previous
//
#include <hip/hip_runtime.h>

typedef __bf16 bf16;
typedef __bf16 bf16x4 __attribute__((ext_vector_type(4)));
typedef __bf16 bf16x8 __attribute__((ext_vector_type(8)));
typedef _Float16 f16;
typedef _Float16 f16x2 __attribute__((ext_vector_type(2)));
typedef _Float16 f16x4 __attribute__((ext_vector_type(4)));
typedef _Float16 f16x8 __attribute__((ext_vector_type(8)));
typedef float f32x4 __attribute__((ext_vector_type(4)));
typedef unsigned int u32x4 __attribute__((ext_vector_type(4)));

#define MFMA16 __builtin_amdgcn_mfma_f32_16x16x32_bf16
#define MFMA16H __builtin_amdgcn_mfma_f32_16x16x32_f16

// async 16B/lane global->LDS copy; HW scatters lane i to lds + i*16 (wave-uniform base)
__device__ __forceinline__ void async16(void* lds, const void* g) {
    __builtin_amdgcn_global_load_lds((const __attribute__((address_space(1))) unsigned int*)g,
                                     (__attribute__((address_space(3))) unsigned int*)lds, 16, 0, 0);
}

// packed f32x2 -> f16x2 (cvt_pkrtz returns __fp16-based vector; bit-cast to _Float16-based)
__device__ __forceinline__ f16x2 pkrtz(float a, float b) {
    return __builtin_bit_cast(f16x2, __builtin_amdgcn_cvt_pkrtz(a, b));
}

__device__ __forceinline__ float fdot2h(f16x2 a, f16x2 b, float c) {
#if __has_builtin(__builtin_amdgcn_fdot2)
    return __builtin_amdgcn_fdot2(a, b, c, false);
#else
    return c + (float)a[0] * (float)b[0] + (float)a[1] * (float)b[1];
#endif
}

// ---------------------------------------------------------------------------
// K0 "prep": weight cvt (blocks 0..255) + three activation transposes
// (s3: 256..767, s4: 768..1023, s5: 1024..1151).
__global__ __launch_bounds__(256) void k_prep(const float* __restrict__ qw, const float* __restrict__ kw,
                                              const float* __restrict__ vw, const float* __restrict__ ow,
                                              bf16* __restrict__ Wb,
                                              const float* __restrict__ s3, const float* __restrict__ s4,
                                              const float* __restrict__ s5,
                                              bf16* __restrict__ s3t, bf16* __restrict__ s45t) {
    __shared__ float T[64][65];
    int bx = blockIdx.x, t = threadIdx.x;
    if (bx < 256) {
        int tt = bx * 256 + t;
        const float* srcs[4] = {qw, kw, vw, ow};
        int which = tt >> 14;
        int idx = (tt & 16383) * 4;
        f32x4 v = *(const f32x4*)(srcs[which] + idx);
        bf16x4 o;
        o[0] = (bf16)v[0]; o[1] = (bf16)v[1]; o[2] = (bf16)v[2]; o[3] = (bf16)v[3];
        *(bf16x4*)(Wb + (size_t)which * 65536 + idx) = o;
        return;
    }
    const float* src; bf16* dst; int N, dstRows, rowOff, x, y, z;
    if (bx < 768)       { int i = bx - 256;  src = s3; dst = s3t;  N = 4096; dstRows = 4096; rowOff = 0;    x = i & 63; y = (i >> 6) & 3; z = i >> 8; }
    else if (bx < 1024) { int i = bx - 768;  src = s4; dst = s45t; N = 2048; dstRows = 3072; rowOff = 0;    x = i & 31; y = (i >> 5) & 3; z = i >> 7; }
    else                { int i = bx - 1024; src = s5; dst = s45t; N = 1024; dstRows = 3072; rowOff = 2048; x = i & 15; y = (i >> 4) & 3; z = i >> 6; }
    int c0 = y * 64, n0 = x * 64, b = z;
    const float* s = src + ((size_t)b * 256 + c0) * N + n0;
#pragma unroll
    for (int i = 0; i < 4; i++) {
        int flat = i * 256 + t;
        int row = flat >> 4;
        int col = (flat & 15) * 4;
        f32x4 v = *(const f32x4*)(s + (size_t)row * N + col);
        T[row][col + 0] = v[0]; T[row][col + 1] = v[1];
        T[row][col + 2] = v[2]; T[row][col + 3] = v[3];
    }
    __syncthreads();
#pragma unroll
    for (int i = 0; i < 4; i++) {
        int flat = i * 256 + t;
        int nrow = flat >> 4;
        int c4 = (flat & 15) * 4;
        bf16x4 o;
        o[0] = (bf16)T[c4 + 0][nrow]; o[1] = (bf16)T[c4 + 1][nrow];
        o[2] = (bf16)T[c4 + 2][nrow]; o[3] = (bf16)T[c4 + 3][nrow];
        *(bf16x4*)(dst + ((size_t)(b * dstRows + rowOff + n0 + nrow)) * 256 + c0 + c4) = o;
    }
}

// ---------------------------------------------------------------------------
// K1 "qkv": Q blocks 0..511 (mode 0), K 512..895 (mode 1), V 896..1279 (mode 2).
// mode 0: Q bf16 [bh][n][32], pre-scaled by 32^-.5*log2e.
// mode 1: K bf16 [bh][n'][32], n' row-permuted within 32-blocks (u=n&31 ->
//         np = ((u>>2)&1)<<4 | (u>>3)<<2 | (u&3)) so two 16-row S^T tiles
//         concatenate into a K=32 MFMA B-operand.
// mode 2: V f16 [bh][32 d][3072 kn], kn permuted per 64-chunk by a d-keyed
//         XOR on 8-elem granules: col = (n&~63) + ((g^(d&7))<<3) + (n&7).
__global__ __launch_bounds__(256) void k_qkv(const bf16* __restrict__ Wb,
                                             const bf16* __restrict__ s3t, const bf16* __restrict__ s45t,
                                             const float* __restrict__ qb, const float* __restrict__ kb,
                                             const float* __restrict__ vb,
                                             bf16* __restrict__ Qb, bf16* __restrict__ Kb,
                                             f16* __restrict__ Vtb, float qscale) {
    int i = blockIdx.x;
    int mode, n0, m0, b, Nrows;
    const bf16 *A, *Bt; const float* bias; float oscale = 1.0f;
    if (i < 512) {
        mode = 0; A = Wb; Bt = s3t; bias = qb; Nrows = 4096; oscale = qscale;
        n0 = (i & 63) * 64; m0 = ((i >> 6) & 3) * 64; b = i >> 8;
    } else if (i < 896) {
        unsigned j = i - 512;
        mode = 1; A = Wb + 65536; Bt = s45t; bias = kb; Nrows = 3072;
        n0 = (j % 48u) * 64; unsigned rr = j / 48u; m0 = (rr & 3) * 64; b = rr >> 2;
    } else {
        unsigned j = i - 896;
        mode = 2; A = Wb + 131072; Bt = s45t; bias = vb; Nrows = 3072;
        n0 = (j % 48u) * 64; unsigned rr = j / 48u; m0 = (rr & 3) * 64; b = rr >> 2;
    }
    __shared__ bf16 As[64 * 40];
    __shared__ bf16 Bs[64 * 40];
    int t = threadIdx.x;
    int w = t >> 6, lane = t & 63;
    int lrow = lane & 15, lk = lane >> 4;
    f32x4 acc[4] = {};
    int r = t >> 2, cc = (t & 3) * 8;
    for (int kc = 0; kc < 256; kc += 32) {
        u32x4 va = *(const u32x4*)(A + (size_t)(m0 + r) * 256 + kc + cc);
        u32x4 vbv = *(const u32x4*)(Bt + ((size_t)b * Nrows + n0 + r) * 256 + kc + cc);
        *(u32x4*)(As + r * 40 + cc) = va;
        *(u32x4*)(Bs + r * 40 + cc) = vbv;
        __syncthreads();
        bf16x8 af = *(const bf16x8*)(As + (w * 16 + lrow) * 40 + lk * 8);
#pragma unroll
        for (int ct = 0; ct < 4; ct++) {
            bf16x8 bfr = *(const bf16x8*)(Bs + (ct * 16 + lrow) * 40 + lk * 8);
            acc[ct] = MFMA16(af, bfr, acc[ct], 0, 0, 0);
        }
        __syncthreads();
    }
    // C/D layout: col = lane&15, row = (lane>>4)*4 + reg  [verified m89/m91]
    int o0 = m0 + w * 16 + lk * 4;
    f32x4 b4 = *(const f32x4*)(bias + o0);
    int head = o0 >> 5;
#pragma unroll
    for (int ct = 0; ct < 4; ct++) {
        int n = n0 + ct * 16 + lrow;
        if (mode == 0) {
            int dd = o0 & 31;
            bf16x4 pv;
#pragma unroll
            for (int j = 0; j < 4; j++) pv[j] = (bf16)((acc[ct][j] + b4[j]) * oscale);
            *(bf16x4*)(Qb + ((size_t)(b * 8 + head) * 4096 + n) * 32 + dd) = pv;
        } else if (mode == 1) {
            int dd = o0 & 31;
            int u = n & 31;
            int np = (n & ~31) | (((u >> 2) & 1) << 4) | ((u >> 3) << 2) | (u & 3);
            bf16x4 pv;
#pragma unroll
            for (int j = 0; j < 4; j++) pv[j] = (bf16)(acc[ct][j] + b4[j]);
            *(bf16x4*)(Kb + ((size_t)(b * 8 + head) * 3072 + np) * 32 + dd) = pv;
        } else {
            int g = (n & 63) >> 3;
#pragma unroll
            for (int j = 0; j < 4; j++) {
                int dd = (o0 & 31) + j;
                int col = (n & ~63) + ((g ^ (dd & 7)) << 3) + (n & 7);
                Vtb[((size_t)(b * 8 + head) * 32 + dd) * 3072 + col] = (f16)(acc[ct][j] + b4[j]);
            }
        }
    }
}

// ---------------------------------------------------------------------------
// K2: attention. S^T = K·Q^T (bf16 16x16x32); K's global row-perm makes two
// 16-row S^T tiles' exp2'd C/D registers a bit-exact K=32 f16 B-operand, so
// PV runs full-rate via mfma_f32_16x16x32_f16 with V^T as A: out^T[d][q] +=
// V^T·P^T, P register-resident. L row-sums: fdot2 + 2 shuffles.
// R9: 2 q-groups per wave (32 q, 128 q/block) to cut unified reg need to ~70
// (accO 16 + aq 8) -> more waves/SIMD resident; grid 2048 = 8 blocks/CU
// available. NO launch_bounds forcing beyond (256,4) — R8 showed forcing the
// cap spills accumulators in-loop (530 MB scratch traffic, 3x regression).
// kn chunk 64, dbuf async LDS; split-kn=4; LDS union: epilogue Tq aliases
// Ks/Vs (16.9 KB total).
__global__ __launch_bounds__(256, 4) void k_attn(const bf16* __restrict__ Q, const bf16* __restrict__ K,
                                                 const f16* __restrict__ Vt,
                                                 f16* __restrict__ Opart, float* __restrict__ Lsum) {
    int bh = blockIdx.y;
    int q0 = blockIdx.x * 128;
    int sp = blockIdx.z;
    int kn0 = sp * 768;
    int t = threadIdx.x, w = t >> 6, lane = t & 63;
    int lrow = lane & 15, lk = lane >> 4;
    __shared__ __align__(16) char smem[16896];
    bf16* Ks = (bf16*)smem;          // [2][64*32]
    f16* Vs = (f16*)(smem + 8192);   // [2][32*64]
    f16* Tq = (f16*)smem;            // epilogue: per-wave 32x34 (aliases Ks/Vs)
    const bf16* kbase = K + (size_t)bh * 3072 * 32;
    const f16* vbase = Vt + (size_t)bh * 32 * 3072;
    const bf16* kg = kbase + (size_t)(kn0 + w * 16 + (lane >> 2)) * 32 + (lane & 3) * 8;
    const f16* vg = vbase + (size_t)(w * 8 + (lane >> 3)) * 3072 + kn0 + (lane & 7) * 8;
    // Q as B-operand: B[k=d=lk*8+j][n=q=lrow], one frag per 16-q group
    bf16x8 aq[2];
#pragma unroll
    for (int qg = 0; qg < 2; ++qg)
        aq[qg] = *(const bf16x8*)(Q + ((size_t)bh * 4096 + q0 + w * 32 + qg * 16 + lrow) * 32 + lk * 8);
    f32x4 accO[2][2] = {};   // [q-group][d-half], out^T: row=d_local, col=q
    float lsum[2] = {0.f, 0.f};
    f32x4 zero = {};
    f16x2 one2; one2[0] = (f16)1.f; one2[1] = (f16)1.f;
    int vkey = lrow & 7;     // V image XOR key = d&7 (same for both d-halves)
    async16(Ks + w * 512, kg);
    async16(Vs + w * 512, vg);
    __syncthreads();
    for (int c = 0; c < 12; ++c) {
        int buf = c & 1;
        if (c < 11) {
            async16(Ks + (buf ^ 1) * 2048 + w * 512, kg + (size_t)(c + 1) * 64 * 32);
            async16(Vs + (buf ^ 1) * 2048 + w * 512, vg + (c + 1) * 64);
        }
        const bf16* ksb = Ks + buf * 2048;
        const f16* vsb = Vs + buf * 2048;
#pragma unroll
        for (int p = 0; p < 2; ++p) {   // two 32-kn chunks
            f32x4 s[2][2];
#pragma unroll
            for (int t2 = 0; t2 < 2; ++t2) {
                bf16x8 kf = *(const bf16x8*)(ksb + (p * 32 + t2 * 16 + lrow) * 32 + lk * 8);
#pragma unroll
                for (int qg = 0; qg < 2; ++qg) s[t2][qg] = MFMA16(kf, aq[qg], zero, 0, 0, 0);
            }
            f16x8 vf0 = *(const f16x8*)(vsb + lrow * 64 + ((((p << 2) | lk) ^ vkey) << 3));
            f16x8 vf1 = *(const f16x8*)(vsb + (16 + lrow) * 64 + ((((p << 2) | lk) ^ vkey) << 3));
#pragma unroll
            for (int qg = 0; qg < 2; ++qg) {   // per-qg: transients die immediately
                f16x2 h0 = pkrtz(__builtin_amdgcn_exp2f(s[0][qg][0]), __builtin_amdgcn_exp2f(s[0][qg][1]));
                f16x2 h1 = pkrtz(__builtin_amdgcn_exp2f(s[0][qg][2]), __builtin_amdgcn_exp2f(s[0][qg][3]));
                f16x2 h2 = pkrtz(__builtin_amdgcn_exp2f(s[1][qg][0]), __builtin_amdgcn_exp2f(s[1][qg][1]));
                f16x2 h3 = pkrtz(__builtin_amdgcn_exp2f(s[1][qg][2]), __builtin_amdgcn_exp2f(s[1][qg][3]));
                f16x8 pk;
                pk[0] = h0[0]; pk[1] = h0[1]; pk[2] = h1[0]; pk[3] = h1[1];
                pk[4] = h2[0]; pk[5] = h2[1]; pk[6] = h3[0]; pk[7] = h3[1];
                lsum[qg] = fdot2h(h0, one2, lsum[qg]);
                lsum[qg] = fdot2h(h1, one2, lsum[qg]);
                lsum[qg] = fdot2h(h2, one2, lsum[qg]);
                lsum[qg] = fdot2h(h3, one2, lsum[qg]);
                accO[qg][0] = MFMA16H(vf0, pk, accO[qg][0], 0, 0, 0);
                accO[qg][1] = MFMA16H(vf1, pk, accO[qg][1], 0, 0, 0);
            }
        }
        __syncthreads();   // also guards Tq aliasing (final iter)
    }
    // L: reduce per-lane partials over lk (lanes lrow, lrow+16, +32, +48)
    int sb = sp * 16 + bh;
#pragma unroll
    for (int qg = 0; qg < 2; ++qg) {
        lsum[qg] += __shfl_xor(lsum[qg], 16, 64);
        lsum[qg] += __shfl_xor(lsum[qg], 32, 64);
    }
    if (lane < 16) {
#pragma unroll
        for (int qg = 0; qg < 2; ++qg)
            Lsum[(size_t)sb * 4096 + q0 + w * 32 + qg * 16 + lane] = lsum[qg];
    }
    // O epilogue: same-wave LDS transpose [d][q] -> coalesced [q][d] f16 stores
    f16* tw = Tq + w * 1088;   // 32 d-rows x 34 (pad)
#pragma unroll
    for (int qg = 0; qg < 2; ++qg)
#pragma unroll
        for (int dh = 0; dh < 2; ++dh)
#pragma unroll
            for (int i = 0; i < 4; ++i)
                tw[(dh * 16 + lk * 4 + i) * 34 + qg * 16 + lrow] = (f16)accO[qg][dh][i];
    int q2 = (lane & 15) * 2, dgrp = (lane >> 4) * 8;
#pragma unroll
    for (int qq = 0; qq < 2; ++qq) {
        f16x8 ov;
#pragma unroll
        for (int dj = 0; dj < 8; ++dj) ov[dj] = tw[(dgrp + dj) * 34 + q2 + qq];
        *(f16x8*)(Opart + ((size_t)sb * 4096 + q0 + w * 32 + q2 + qq) * 32 + dgrp) = ov;
    }
}

// ---------------------------------------------------------------------------
// K3 "oln": o-projection + split-kn combine + bias + residual + LayerNorm +
// output transpose, all in one kernel. Block = 32 q x 256 c (full channel row
// -> LN is block-local). Residual from bf16 s3t [b][n][256] (error << thresh).
__global__ __launch_bounds__(256) void k_oln(const bf16* __restrict__ A, const f16* __restrict__ Opart,
                                             const float* __restrict__ Ls, const float* __restrict__ bias,
                                             const bf16* __restrict__ s3t,
                                             const float* __restrict__ lnw, const float* __restrict__ lnb,
                                             float* __restrict__ out) {
    int i = blockIdx.x;
    int b = i >> 7, n0 = (i & 127) * 32;
    __shared__ __align__(16) char smem[34176];
    bf16* As = (bf16*)smem;                 // 256 x 40 bf16 = 20480 B (GEMM phase)
    bf16* Bs = (bf16*)(smem + 20480);       // 32 x 40 bf16 = 2560 B
    float* T = (float*)smem;                // 32 x 257 f32 = 32896 B (LN phase, aliases As/Bs)
    float* ps = (float*)(smem + 32896);     // [4 w][32 n] partial sums
    float* pq = (float*)(smem + 33408);     // [4 w][32 n] partial sumsq
    float* mu_s = (float*)(smem + 33920);   // [32]
    float* rs_s = (float*)(smem + 34048);   // [32]
    int t = threadIdx.x, w = t >> 6, lane = t & 63;
    int lrow = lane & 15, lk = lane >> 4;
    f32x4 acc[4][2] = {};                   // [mt: c-64-block][ct: 16-q group]
    int rB = t >> 3, cgB = (t & 7) * 4;     // B staging: row q, 4-d group
    int q = n0 + rB;
    const size_t SPS = (size_t)16 * 4096 * 32;   // Opart sp stride (elems)
    for (int kc = 0; kc < 256; kc += 32) {
        int bh = b * 8 + (kc >> 5);
        // A staging: thread t = row o, 32 c = 4 x 16B
        const bf16* ar = A + (size_t)t * 256 + kc;
        u32x4 va0 = *(const u32x4*)(ar);
        u32x4 va1 = *(const u32x4*)(ar + 8);
        u32x4 va2 = *(const u32x4*)(ar + 16);
        u32x4 va3 = *(const u32x4*)(ar + 24);
        // B combine: sum 4 split-kn partials, divide by total L
        float l = 0.f;
#pragma unroll
        for (int sp = 0; sp < 4; ++sp) l += Ls[(size_t)(sp * 16 + bh) * 4096 + q];
        float rl = 1.0f / l;
        const f16* obp = Opart + ((size_t)bh * 4096 + q) * 32 + cgB;
        f32x4 sv = {};
#pragma unroll
        for (int sp = 0; sp < 4; ++sp) {
            f16x4 av = *(const f16x4*)(obp + sp * SPS);
#pragma unroll
            for (int j = 0; j < 4; ++j) sv[j] += (float)av[j];
        }
        bf16x4 bb;
#pragma unroll
        for (int j = 0; j < 4; ++j) bb[j] = (bf16)(sv[j] * rl);
        *(u32x4*)(As + t * 40 + 0) = va0;
        *(u32x4*)(As + t * 40 + 8) = va1;
        *(u32x4*)(As + t * 40 + 16) = va2;
        *(u32x4*)(As + t * 40 + 24) = va3;
        *(bf16x4*)(Bs + rB * 40 + cgB) = bb;
        __syncthreads();
#pragma unroll
        for (int mt = 0; mt < 4; ++mt) {
            bf16x8 af = *(const bf16x8*)(As + (mt * 64 + w * 16 + lrow) * 40 + lk * 8);
#pragma unroll
            for (int ct = 0; ct < 2; ++ct) {
                bf16x8 bfr = *(const bf16x8*)(Bs + (ct * 16 + lrow) * 40 + lk * 8);
                acc[mt][ct] = MFMA16(af, bfr, acc[mt][ct], 0, 0, 0);
            }
        }
        __syncthreads();   // last iter: frees As/Bs for the T alias below
    }
    // epilogue: bias + residual; write raw values to T; accumulate LN stats
    float wsum[2] = {0.f, 0.f}, wsq[2] = {0.f, 0.f};
#pragma unroll
    for (int ct = 0; ct < 2; ++ct) {
        int n = ct * 16 + lrow;
#pragma unroll
        for (int mt = 0; mt < 4; ++mt) {
            int c0 = mt * 64 + w * 16 + lk * 4;
            f32x4 b4 = *(const f32x4*)(bias + c0);
            bf16x4 rv = *(const bf16x4*)(s3t + ((size_t)b * 4096 + n0 + n) * 256 + c0);
#pragma unroll
            for (int j = 0; j < 4; ++j) {
                float v = acc[mt][ct][j] + b4[j] + (float)rv[j];
                T[n * 257 + c0 + j] = v;
                wsum[ct] += v;
                wsq[ct] += v * v;
            }
        }
    }
#pragma unroll
    for (int ct = 0; ct < 2; ++ct) {
        wsum[ct] += __shfl_xor(wsum[ct], 16, 64);
        wsum[ct] += __shfl_xor(wsum[ct], 32, 64);
        wsq[ct] += __shfl_xor(wsq[ct], 16, 64);
        wsq[ct] += __shfl_xor(wsq[ct], 32, 64);
    }
    if (lk == 0) {
#pragma unroll
        for (int ct = 0; ct < 2; ++ct) {
            ps[w * 32 + ct * 16 + lrow] = wsum[ct];
            pq[w * 32 + ct * 16 + lrow] = wsq[ct];
        }
    }
    __syncthreads();
    if (t < 32) {
        float S = ps[t] + ps[32 + t] + ps[64 + t] + ps[96 + t];
        float Q2 = pq[t] + pq[32 + t] + pq[64 + t] + pq[96 + t];
        float m = S * (1.0f / 256.0f);
        mu_s[t] = m;
        rs_s[t] = rsqrtf(Q2 * (1.0f / 256.0f) - m * m + 1e-5f);
    }
    __syncthreads();
    // write out[b][c][n0..n0+31], coalesced along n
    int cb = t >> 3, n4 = (t & 7) * 4;
#pragma unroll
    for (int cc8 = 0; cc8 < 8; ++cc8) {
        int c = cb + cc8 * 32;
        float wv = lnw[c], bv = lnb[c];
        f32x4 o;
#pragma unroll
        for (int k2 = 0; k2 < 4; ++k2)
            o[k2] = (T[(n4 + k2) * 257 + c] - mu_s[n4 + k2]) * rs_s[n4 + k2] * wv + bv;
        *(f32x4*)(out + ((size_t)b * 256 + c) * 4096 + n0 + n4) = o;
    }
}

// ---------------------------------------------------------------------------
extern "C" void kernel_launch(void* const* d_in, const int* in_sizes, int n_in,
                              void* d_out, int out_size, void* d_ws, size_t ws_size,
                              hipStream_t stream) {
    const float* s3  = (const float*)d_in[0];
    const float* s4  = (const float*)d_in[1];
    const float* s5  = (const float*)d_in[2];
    const float* qw  = (const float*)d_in[3];
    const float* qb  = (const float*)d_in[4];
    const float* kw  = (const float*)d_in[5];
    const float* kb  = (const float*)d_in[6];
    const float* vw  = (const float*)d_in[7];
    const float* vb  = (const float*)d_in[8];
    const float* ow  = (const float*)d_in[9];
    const float* ob  = (const float*)d_in[10];
    const float* lnw = (const float*)d_in[11];
    const float* lnb = (const float*)d_in[12];
    float* out = (float*)d_out;
    char* ws = (char*)d_ws;

    // workspace layout (~34.5 MB peak):
    bf16* Wb    = (bf16*)(ws);                          // 512 KB @ 0
    bf16* s3t   = (bf16*)(ws + (512ull << 10));         // 4 MB  @ 0.5 MB (live till k_oln)
    bf16* s45t  = (bf16*)(ws + (4608ull << 10));        // 3 MB  @ 4.5 MB
    bf16* Qb    = (bf16*)(ws + (7680ull << 10));        // 4 MB  @ 7.5 MB
    bf16* Kb    = Qb + (2ull * 8 * 4096 * 32);          // 3 MB  @ 11.5 MB
    f16*  Vtb   = (f16*)(Kb + (2ull * 8 * 3072 * 32));  // 3 MB  @ 14.5 MB
    f16*  Opart = (f16*)(ws + (17920ull << 10));        // 16 MB @ 17.5 MB (f16 [4sp][16bh][4096q][32d])
    float* Lsum = (float*)(ws + (34304ull << 10));      // 1 MB  @ 33.5 MB

    const float qscale = 0.17677669529663688f * 1.4426950408889634f;  // 32^-0.5 * log2(e)

    k_prep<<<1152, 256, 0, stream>>>(qw, kw, vw, ow, Wb, s3, s4, s5, s3t, s45t);
    k_qkv<<<1280, 256, 0, stream>>>(Wb, s3t, s45t, qb, kb, vb, Qb, Kb, Vtb, qscale);
    k_attn<<<dim3(32, 16, 4), 256, 0, stream>>>(Qb, Kb, Vtb, Opart, Lsum);
    k_oln<<<256, 256, 0, stream>>>(Wb + 196608, Opart, Lsum, ob, s3t, lnw, lnb, out);
}